// Round 16
// baseline (362.199 us; speedup 1.0000x reference)
//
#include <hip/hip_runtime.h>
#include <hip/hip_bf16.h>

#define B_ 16
#define S_ 4096
#define C_ 320
#define KK_ 77
#define D_ 768
#define H_ 8
#define DH_ 40
#define KP_ 80           // padded keys per head
#define NP_ (H_ * KP_)   // 640
#define TAU_ 0.1f
#define GAMMA_ 1.0f
#define EPS_ 1e-12f

typedef __bf16 bf16x8 __attribute__((ext_vector_type(8)));
typedef float f32x4 __attribute__((ext_vector_type(4)));
typedef unsigned short ushort8v __attribute__((ext_vector_type(8)));
typedef unsigned int u32;

#define WAITV(N)  asm volatile("s_waitcnt vmcnt(" #N ")" ::: "memory")
#define WAITLG()  asm volatile("s_waitcnt lgkmcnt(0)" ::: "memory")
#define BAR()     __builtin_amdgcn_s_barrier()

__device__ __forceinline__ unsigned short f2bf(float f) {
    union { float f; unsigned u; } v; v.f = f;
    unsigned r = v.u + 0x7fffu + ((v.u >> 16) & 1u);
    return (unsigned short)(r >> 16);
}

// async 16B-per-lane global->LDS DMA (lds dest = wave-uniform base + lane*16)
__device__ __forceinline__ void gld16(const unsigned short* g, char* l) {
    __builtin_amdgcn_global_load_lds(
        (const __attribute__((address_space(1))) u32*)g,
        (__attribute__((address_space(3))) u32*)l, 16, 0, 0);
}

// ---------------------------------------------------------------- build_M
__global__ __launch_bounds__(256) void build_M(const float* __restrict__ Wq,
        const float* __restrict__ Wk, const float* __restrict__ Wv,
        const float* __restrict__ Wo, unsigned short* __restrict__ Bmat) {
    const int Dk = blockIdx.x * 256 + threadIdx.x;     // 0..767
    const int h = blockIdx.y;
    const int which = blockIdx.z >> 2;
    const int c0 = (blockIdx.z & 3) * 80;
    __shared__ float wlds[80 * 44];
    for (int i = threadIdx.x; i < 80 * DH_; i += 256) {
        int c = i / DH_, d = i % DH_;
        wlds[c * 44 + d] = which
            ? Wo[(size_t)(h * DH_ + d) * C_ + (c0 + c)]
            : Wq[(size_t)(c0 + c) * C_ + h * DH_ + d];
    }
    float a[DH_];
    const float* Arow = (which ? Wv : Wk) + (size_t)Dk * C_ + h * DH_;
    #pragma unroll
    for (int d = 0; d < DH_; ++d) a[d] = Arow[d];
    __syncthreads();
    const float scale = 0.15811388300841898f;          // 1/sqrt(40)
    for (int c = 0; c < 80; ++c) {
        float s = 0.f;
        #pragma unroll
        for (int q = 0; q < 10; ++q) {
            float4 wv4 = *(const float4*)&wlds[c * 44 + q * 4];
            s += a[q * 4 + 0] * wv4.x + a[q * 4 + 1] * wv4.y
               + a[q * 4 + 2] * wv4.z + a[q * 4 + 3] * wv4.w;
        }
        if (!which) s *= scale;
        int n = which * 2560 + h * C_ + c0 + c;
        Bmat[(size_t)n * D_ + Dk] = f2bf(s);
    }
}

// ---------------------------------------------------------------- prep_ehs
__global__ __launch_bounds__(256) void prep_ehs(const float* __restrict__ ehs,
        const float* __restrict__ harm, unsigned short* __restrict__ ehs_bf,
        float* __restrict__ pen) {
    const int w = threadIdx.x >> 6, l = threadIdx.x & 63;
    const int kk = blockIdx.x * 4 + w, b = blockIdx.y;
    const size_t obase = ((size_t)b * KP_ + kk) * D_;
    if (kk >= KK_) {
        #pragma unroll
        for (int j = 0; j < 12; ++j) ehs_bf[obase + l + j * 64] = 0;
        if (l == 0) pen[b * KP_ + kk] = 0.f;
        return;
    }
    const float* er = ehs + ((size_t)b * KK_ + kk) * D_;
    float ss = 0.f, dd = 0.f, hh = 0.f;
    #pragma unroll
    for (int j = 0; j < 12; ++j) {
        float e = er[l + j * 64], hv = harm[l + j * 64];
        ehs_bf[obase + l + j * 64] = f2bf(e);
        ss += e * e; dd += e * hv; hh += hv * hv;
    }
    #pragma unroll
    for (int off = 32; off; off >>= 1) {
        ss += __shfl_xor(ss, off);
        dd += __shfl_xor(dd, off);
        hh += __shfl_xor(hh, off);
    }
    if (l == 0) {
        float cs = dd / (fmaxf(sqrtf(ss), EPS_) * fmaxf(sqrtf(hh), EPS_));
        pen[b * KP_ + kk] = GAMMA_ * fmaxf(cs - TAU_, 0.f);
    }
}

// ---------------------------------------------------------------- gemm_WpU
__global__ __launch_bounds__(1024) void gemm_WpU(
        const unsigned short* __restrict__ ehs_bf,
        const unsigned short* __restrict__ Bmat,
        unsigned short* __restrict__ Wp, unsigned short* __restrict__ U) {
    const int id = blockIdx.x;               // 160 = 16 b * 10 nt
    const int b = id & 15, nt = id >> 4;
    const int tid = threadIdx.x, w = tid >> 6, l = tid & 63;
    const int lrow = l & 15, lgrp = l >> 4, lk = lgrp * 8;
    __shared__ unsigned short Al[80 * 768];  // 122880 B, swizzled
    char* lds = (char*)Al;

    const unsigned short* Ag = ehs_bf + (size_t)b * KP_ * D_;
    #pragma unroll
    for (int it = 0; it < 8; ++it) {
        int ch = tid + it * 1024;
        if (ch < 7680) {
            int byte = ch * 16, row = byte / 1536;
            int a = byte ^ ((row & 7) << 4);
            *(ushort8v*)(lds + a) = *(const ushort8v*)(Ag + ch * 8);
        }
    }
    const int n0 = nt * 512 + w * 32;
    const unsigned short* Br = Bmat + (size_t)(n0 + lrow) * D_ + lk;
    bf16x8 bC[2], bN[2];
    #pragma unroll
    for (int nf = 0; nf < 2; ++nf)
        bC[nf] = *(const bf16x8*)(Br + (size_t)nf * 16 * D_);
    __syncthreads();

    f32x4 acc[5][2];
    #pragma unroll
    for (int mf = 0; mf < 5; ++mf)
        #pragma unroll
        for (int nf = 0; nf < 2; ++nf) acc[mf][nf] = (f32x4){0.f, 0.f, 0.f, 0.f};
    #pragma unroll
    for (int ks = 0; ks < D_ / 32; ++ks) {
        if (ks < D_ / 32 - 1) {
            #pragma unroll
            for (int nf = 0; nf < 2; ++nf)
                bN[nf] = *(const bf16x8*)(Br + (size_t)nf * 16 * D_ + (ks + 1) * 32);
        }
        bf16x8 af[5];
        #pragma unroll
        for (int mf = 0; mf < 5; ++mf) {
            int row = mf * 16 + lrow;
            int a = (row * 1536 + (ks * 32 + lk) * 2) ^ ((row & 7) << 4);
            af[mf] = *(const bf16x8*)(lds + a);
        }
        __builtin_amdgcn_s_setprio(1);
        #pragma unroll
        for (int mf = 0; mf < 5; ++mf)
            #pragma unroll
            for (int nf = 0; nf < 2; ++nf)
                acc[mf][nf] = __builtin_amdgcn_mfma_f32_16x16x32_bf16(
                    af[mf], bC[nf], acc[mf][nf], 0, 0, 0);
        __builtin_amdgcn_s_setprio(0);
        #pragma unroll
        for (int nf = 0; nf < 2; ++nf) bC[nf] = bN[nf];
    }
    #pragma unroll
    for (int nf = 0; nf < 2; ++nf) {
        const int col = n0 + nf * 16 + lrow;
        if (col < 2560) {
            const int h = col / C_, c = col % C_;
            #pragma unroll
            for (int mf = 0; mf < 5; ++mf)
                #pragma unroll
                for (int r = 0; r < 4; ++r) {
                    int kk = mf * 16 + lgrp * 4 + r;
                    Wp[((size_t)b * NP_ + h * KP_ + kk) * C_ + c] = f2bf(acc[mf][nf][r]);
                }
        } else {
            const int n2 = col - 2560;
            const int h = n2 / C_, c = n2 % C_;
            #pragma unroll
            for (int mf = 0; mf < 5; ++mf)
                #pragma unroll
                for (int r = 0; r < 4; ++r) {
                    int kk = mf * 16 + lgrp * 4 + r;
                    U[((size_t)b * C_ + c) * NP_ + h * KP_ + kk] = f2bf(acc[mf][nf][r]);
                }
        }
    }
}

// ---------------------------------------------------------------- fused attn
// R15: 512 blocks x 1024 threads (16 waves), 128 S-rows, 160KB LDS.
// Wp/U staged ONCE per 128 rows (2x amortization vs R12) with R12's exact
// full-line layouts; acc stays [5][4]=80/wave via 2-waves-per-head mh-split.
// Phase 2: P via pk regs -> 64-kk chunks [128][128B] dbuf (R14 scheme,
// verified correct), U [320][128B] K=64 slices, roles 4m x 4c.
__global__ __launch_bounds__(1024) void fused_attn(
        const float* __restrict__ hs, const unsigned short* __restrict__ Wp,
        const unsigned short* __restrict__ U, const float* __restrict__ pen,
        const float* __restrict__ bo, float* __restrict__ out) {
    const int id = blockIdx.x;                  // 512 = 8 xcd * 64
    const int xcd = id & 7, rest = id >> 3;     // rest 0..63
    const int b = xcd * 2 + (rest >> 5);        // 2 batches per XCD
    const int s0 = (rest & 31) * 128;
    __shared__ __align__(16) char smem[163840];
    char* HS  = smem;                           // [0,81920)  hs [128][640B] swz
    char* WB  = smem + 81920;                   // [81920,163840) Wp K=64 slice
    char* PC0 = smem;                           // [0,16384)   P chunk dbuf
    char* PC1 = smem + 16384;                   // [16384,32768)
    char* UB  = smem + 32768;                   // [32768,73728) U K=64 slice
    const int tid = threadIdx.x, w = tid >> 6, l = tid & 63;
    const int lrow = l & 15, lgrp = l >> 4;
    const int h = w & 7, mh = w >> 3;           // phase-1: 2 waves per head
    const int mgrp = w & 3, cgrp = w >> 2;      // phase-2: 4m x 4c

    const unsigned short* Wpb = Wp + (size_t)b * NP_ * C_;
    const unsigned short* Ub  = U  + (size_t)b * C_ * NP_;

    // Wp K=64 slice s -> [n 640][128B]; src chunk (q^(n&7)); 5 instr/wave
    auto stage_wp = [&](int s) {
        #pragma unroll
        for (int j = 0; j < 5; ++j) {
            int ch = w * 320 + j * 64 + l;      // 0..5119
            int n = ch >> 3, q = ch & 7;
            gld16(Wpb + (size_t)n * C_ + s * 64 + ((q ^ (n & 7)) << 3),
                  WB + ch * 16);
        }
    };
    // U K=64 slice t -> [c 320][128B]; src chunk (q^(c&7)); 3/2 instr/wave
    auto stage_u = [&](int t) {
        if (w < 8) {
            #pragma unroll
            for (int j = 0; j < 3; ++j) {
                int ch = w * 192 + j * 64 + l;  // 0..1535
                int c = ch >> 3, q = ch & 7;
                gld16(Ub + (size_t)c * NP_ + t * 64 + ((q ^ (c & 7)) << 3),
                      UB + ch * 16);
            }
        } else {
            #pragma unroll
            for (int j = 0; j < 2; ++j) {
                int ch = 1536 + (w - 8) * 128 + j * 64 + l;  // 1536..2559
                int c = ch >> 3, q = ch & 7;
                gld16(Ub + (size_t)c * NP_ + t * 64 + ((q ^ (c & 7)) << 3),
                      UB + ch * 16);
            }
        }
    };

    // ---- prologue: hs 128x320 f32 -> bf16 into HS (swizzled), sync, slice 0
    const float4* hv = (const float4*)(hs + ((size_t)b * S_ + s0) * C_);
    #pragma unroll
    for (int it = 0; it < 10; ++it) {           // 10*1024 = 10240 float4
        int i = tid + it * 1024;
        float4 v = hv[i];
        int r = i / 80, c = (i * 4) % C_;
        ushort4 u;
        u.x = f2bf(v.x); u.y = f2bf(v.y); u.z = f2bf(v.z); u.w = f2bf(v.w);
        int a = (r * 640 + c * 2) ^ ((r & 7) << 4);
        *(ushort4*)(HS + a) = u;
    }
    __syncthreads();        // drains hv vmem + hs ds_writes; HS visible
    stage_wp(0);

    // ---- phase 1: D[kk][m], 5 K=64 slices, single WB, stage-after-read
    f32x4 acc[5][4];
    #pragma unroll
    for (int nf = 0; nf < 5; ++nf)
        #pragma unroll
        for (int mf = 0; mf < 4; ++mf) acc[nf][mf] = (f32x4){0.f, 0.f, 0.f, 0.f};
    #pragma unroll
    for (int s = 0; s < 5; ++s) {
        WAITV(0);                               // own chunks of slice s done
        BAR();                                  // slice s fully landed
        bf16x8 bC[5][2], hf[4][2];
        #pragma unroll
        for (int nf = 0; nf < 5; ++nf) {
            int n = h * KP_ + nf * 16 + lrow;
            #pragma unroll
            for (int ss = 0; ss < 2; ++ss)
                bC[nf][ss] = *(const bf16x8*)(WB + n * 128 +
                    ((ss * 64 + lgrp * 16) ^ ((n & 7) << 4)));
        }
        #pragma unroll
        for (int mf = 0; mf < 4; ++mf) {
            int row = mh * 64 + mf * 16 + lrow;
            #pragma unroll
            for (int ss = 0; ss < 2; ++ss) {
                int ks32 = 2 * s + ss;
                int a = (row * 640 + ks32 * 64 + lgrp * 16) ^ ((row & 7) << 4);
                hf[mf][ss] = *(const bf16x8*)(HS + a);
            }
        }
        WAITLG();                               // reads in regs
        BAR();                                  // all waves done reading WB
        if (s < 4) stage_wp(s + 1);             // refill; lands under MFMA
        __builtin_amdgcn_s_setprio(1);
        #pragma unroll
        for (int ss = 0; ss < 2; ++ss)
            #pragma unroll
            for (int nf = 0; nf < 5; ++nf)
                #pragma unroll
                for (int mf = 0; mf < 4; ++mf)
                    acc[nf][mf] = __builtin_amdgcn_mfma_f32_16x16x32_bf16(
                        bC[nf][ss], hf[mf][ss], acc[nf][mf], 0, 0, 0);
        __builtin_amdgcn_s_setprio(0);
    }
    // s=4 post-read BAR certified HS + WB reads done everywhere.

    // issue U slice 0 now (overlaps softmax); then penalty loads
    stage_u(0);
    float4 pv4[5];
    #pragma unroll
    for (int nf = 0; nf < 5; ++nf)
        pv4[nf] = *(const float4*)(pen + b * KP_ + nf * 16 + lgrp * 4);

    // ---- softmax + pack P into pk regs (20 VGPR, live through phase 2)
    ushort4 pk[4][5];
    #pragma unroll
    for (int mf = 0; mf < 4; ++mf) {
        float mx = -1e30f;
        #pragma unroll
        for (int nf = 0; nf < 5; ++nf)
            #pragma unroll
            for (int r = 0; r < 4; ++r) {
                float x = acc[nf][mf][r] - ((const float*)&pv4[nf])[r];
                if (nf == 4 && r >= 1) x = (lgrp == 3) ? -1e30f : x;  // kk 77..79
                acc[nf][mf][r] = x;
                mx = fmaxf(mx, x);
            }
        mx = fmaxf(mx, __shfl_xor(mx, 16));
        mx = fmaxf(mx, __shfl_xor(mx, 32));
        float sum = 0.f;
        #pragma unroll
        for (int nf = 0; nf < 5; ++nf)
            #pragma unroll
            for (int r = 0; r < 4; ++r) {
                float e = __expf(acc[nf][mf][r] - mx);
                acc[nf][mf][r] = e; sum += e;
            }
        sum += __shfl_xor(sum, 16);
        sum += __shfl_xor(sum, 32);
        float inv = 1.f / sum;
        #pragma unroll
        for (int nf = 0; nf < 5; ++nf) {
            ushort4 u;
            u.x = f2bf(acc[nf][mf][0] * inv);
            u.y = f2bf(acc[nf][mf][1] * inv);
            u.z = f2bf(acc[nf][mf][2] * inv);
            u.w = f2bf(acc[nf][mf][3] * inv);
            pk[mf][nf] = u;
        }
    }

    // head-0 waves write P chunk 0 (kk 0..63 = nf 0..3) into PC0
    if (h == 0) {
        #pragma unroll
        for (int nf = 0; nf < 4; ++nf) {
            int kk2 = (nf * 16 + lgrp * 4) * 2;
            #pragma unroll
            for (int mf = 0; mf < 4; ++mf) {
                int row = mh * 64 + mf * 16 + lrow;
                *(ushort4*)(PC0 + ((row * 128 + kk2) ^ ((row & 7) << 4))) = pk[mf][nf];
            }
        }
    }
    WAITV(0);                                   // U slice 0 (+pen) landed
    WAITLG();                                   // PC0 ds_writes done
    BAR();                                      // PC0 + U0 visible block-wide

    // ---- phase 2: out = P @ U, 10 K=64 steps; P chunks fed from pk regs
    f32x4 acc2[5][2];
    #pragma unroll
    for (int nf = 0; nf < 5; ++nf)
        #pragma unroll
        for (int mf = 0; mf < 2; ++mf) acc2[nf][mf] = (f32x4){0.f, 0.f, 0.f, 0.f};
    #pragma unroll
    for (int t = 0; t < 10; ++t) {
        char* pc = (t & 1) ? PC1 : PC0;
        bf16x8 pa[2][2], uf[5][2];
        #pragma unroll
        for (int mf = 0; mf < 2; ++mf) {
            int row = mgrp * 32 + mf * 16 + lrow;
            #pragma unroll
            for (int ss = 0; ss < 2; ++ss)
                pa[mf][ss] = *(const bf16x8*)(pc +
                    ((row * 128 + ss * 64 + lgrp * 16) ^ ((row & 7) << 4)));
        }
        #pragma unroll
        for (int nf = 0; nf < 5; ++nf) {
            int c = cgrp * KP_ + nf * 16 + lrow;
            #pragma unroll
            for (int ss = 0; ss < 2; ++ss)
                uf[nf][ss] = *(const bf16x8*)(UB + c * 128 +
                    ((ss * 64 + lgrp * 16) ^ ((c & 7) << 4)));
        }
        WAITLG();                               // reads in regs
        BAR();                                  // all waves done reading pc+UB
        if (t < 9) {
            char* pcn = ((t + 1) & 1) ? PC1 : PC0;
            #pragma unroll
            for (int nf = 0; nf < 5; ++nf) {
                if (((h * KP_ + nf * 16) >> 6) == t + 1) {   // wave-uniform
                    int kk2 = (h * KP_ + nf * 16 + lgrp * 4 - (t + 1) * 64) * 2;
                    #pragma unroll
                    for (int mf = 0; mf < 4; ++mf) {
                        int row = mh * 64 + mf * 16 + lrow;
                        *(ushort4*)(pcn + ((row * 128 + kk2) ^ ((row & 7) << 4)))
                            = pk[mf][nf];
                    }
                }
            }
            stage_u(t + 1);                     // refill UB; lands under MFMA
        }
        __builtin_amdgcn_s_setprio(1);
        #pragma unroll
        for (int ss = 0; ss < 2; ++ss)
            #pragma unroll
            for (int nf = 0; nf < 5; ++nf)
                #pragma unroll
                for (int mf = 0; mf < 2; ++mf)
                    acc2[nf][mf] = __builtin_amdgcn_mfma_f32_16x16x32_bf16(
                        pa[mf][ss], uf[nf][ss], acc2[nf][mf], 0, 0, 0);
        __builtin_amdgcn_s_setprio(0);
        if (t < 9) {
            WAITV(0);                           // own U DMA done
            WAITLG();                           // own PC writes done
            BAR();                              // chunk t+1 + slice t+1 visible
        }
    }

    // ---- epilogue
    float bov[5];
    #pragma unroll
    for (int nf = 0; nf < 5; ++nf) bov[nf] = bo[cgrp * KP_ + nf * 16 + lrow];
    float* op = out + ((size_t)b * S_ + s0) * C_;
    #pragma unroll
    for (int mf = 0; mf < 2; ++mf)
        #pragma unroll
        for (int r = 0; r < 4; ++r)
            #pragma unroll
            for (int nf = 0; nf < 5; ++nf)
                op[(size_t)(mgrp * 32 + mf * 16 + lgrp * 4 + r) * C_ +
                   cgrp * KP_ + nf * 16 + lrow] = acc2[nf][mf][r] + bov[nf];
}

// ---------------------------------------------------------------- launch
extern "C" void kernel_launch(void* const* d_in, const int* in_sizes, int n_in,
                              void* d_out, int out_size, void* d_ws, size_t ws_size,
                              hipStream_t stream) {
    const float* hs   = (const float*)d_in[0];
    const float* ehs  = (const float*)d_in[1];
    const float* harm = (const float*)d_in[2];
    const float* Wq   = (const float*)d_in[3];
    const float* Wk   = (const float*)d_in[4];
    const float* Wv   = (const float*)d_in[5];
    const float* Wo   = (const float*)d_in[6];
    const float* bo   = (const float*)d_in[7];
    float* out = (float*)d_out;

    char* ws = (char*)d_ws;
    unsigned short* ehs_bf = (unsigned short*)(ws);             //  1,966,080
    unsigned short* Bmat   = (unsigned short*)(ws + 1966080);   //  7,864,320
    float*          pen    = (float*)        (ws + 9830400);    //      5,120
    unsigned short* Wp     = (unsigned short*)(ws + 9835520);   //  6,553,600
    unsigned short* U      = (unsigned short*)(ws + 16389120);  //  6,553,600

    build_M <<<dim3(3, 8, 8),  256, 0, stream>>>(Wq, Wk, Wv, Wo, Bmat);
    prep_ehs<<<dim3(20, 16),   256, 0, stream>>>(ehs, harm, ehs_bf, pen);
    gemm_WpU<<<dim3(160),     1024, 0, stream>>>(ehs_bf, Bmat, Wp, U);
    fused_attn<<<dim3(512),   1024, 0, stream>>>(hs, Wp, U, pen, bo, out);
}

// Round 17
// 359.336 us; speedup vs baseline: 1.0080x; 1.0080x over previous
//
#include <hip/hip_runtime.h>
#include <hip/hip_bf16.h>

#define B_ 16
#define S_ 4096
#define C_ 320
#define KK_ 77
#define D_ 768
#define H_ 8
#define DH_ 40
#define KP_ 80           // padded keys per head
#define NP_ (H_ * KP_)   // 640
#define TAU_ 0.1f
#define GAMMA_ 1.0f
#define EPS_ 1e-12f

typedef __bf16 bf16x8 __attribute__((ext_vector_type(8)));
typedef float f32x4 __attribute__((ext_vector_type(4)));
typedef unsigned short ushort8v __attribute__((ext_vector_type(8)));
typedef unsigned int u32;

#define WAITV(N)  asm volatile("s_waitcnt vmcnt(" #N ")" ::: "memory")
#define WAITLG()  asm volatile("s_waitcnt lgkmcnt(0)" ::: "memory")
#define BAR()     __builtin_amdgcn_s_barrier()

__device__ __forceinline__ unsigned short f2bf(float f) {
    union { float f; unsigned u; } v; v.f = f;
    unsigned r = v.u + 0x7fffu + ((v.u >> 16) & 1u);
    return (unsigned short)(r >> 16);
}

// async 16B-per-lane global->LDS DMA (lds dest = wave-uniform base + lane*16)
__device__ __forceinline__ void gld16(const unsigned short* g, char* l) {
    __builtin_amdgcn_global_load_lds(
        (const __attribute__((address_space(1))) u32*)g,
        (__attribute__((address_space(3))) u32*)l, 16, 0, 0);
}

// ---------------------------------------------------------------- build_M
__global__ __launch_bounds__(256) void build_M(const float* __restrict__ Wq,
        const float* __restrict__ Wk, const float* __restrict__ Wv,
        const float* __restrict__ Wo, unsigned short* __restrict__ Bmat) {
    const int Dk = blockIdx.x * 256 + threadIdx.x;     // 0..767
    const int h = blockIdx.y;
    const int which = blockIdx.z >> 2;
    const int c0 = (blockIdx.z & 3) * 80;
    __shared__ float wlds[80 * 44];
    for (int i = threadIdx.x; i < 80 * DH_; i += 256) {
        int c = i / DH_, d = i % DH_;
        wlds[c * 44 + d] = which
            ? Wo[(size_t)(h * DH_ + d) * C_ + (c0 + c)]
            : Wq[(size_t)(c0 + c) * C_ + h * DH_ + d];
    }
    float a[DH_];
    const float* Arow = (which ? Wv : Wk) + (size_t)Dk * C_ + h * DH_;
    #pragma unroll
    for (int d = 0; d < DH_; ++d) a[d] = Arow[d];
    __syncthreads();
    const float scale = 0.15811388300841898f;          // 1/sqrt(40)
    for (int c = 0; c < 80; ++c) {
        float s = 0.f;
        #pragma unroll
        for (int q = 0; q < 10; ++q) {
            float4 wv4 = *(const float4*)&wlds[c * 44 + q * 4];
            s += a[q * 4 + 0] * wv4.x + a[q * 4 + 1] * wv4.y
               + a[q * 4 + 2] * wv4.z + a[q * 4 + 3] * wv4.w;
        }
        if (!which) s *= scale;
        int n = which * 2560 + h * C_ + c0 + c;
        Bmat[(size_t)n * D_ + Dk] = f2bf(s);
    }
}

// ---------------------------------------------------------------- prep_ehs
__global__ __launch_bounds__(256) void prep_ehs(const float* __restrict__ ehs,
        const float* __restrict__ harm, unsigned short* __restrict__ ehs_bf,
        float* __restrict__ pen) {
    const int w = threadIdx.x >> 6, l = threadIdx.x & 63;
    const int kk = blockIdx.x * 4 + w, b = blockIdx.y;
    const size_t obase = ((size_t)b * KP_ + kk) * D_;
    if (kk >= KK_) {
        #pragma unroll
        for (int j = 0; j < 12; ++j) ehs_bf[obase + l + j * 64] = 0;
        if (l == 0) pen[b * KP_ + kk] = 0.f;
        return;
    }
    const float* er = ehs + ((size_t)b * KK_ + kk) * D_;
    float ss = 0.f, dd = 0.f, hh = 0.f;
    #pragma unroll
    for (int j = 0; j < 12; ++j) {
        float e = er[l + j * 64], hv = harm[l + j * 64];
        ehs_bf[obase + l + j * 64] = f2bf(e);
        ss += e * e; dd += e * hv; hh += hv * hv;
    }
    #pragma unroll
    for (int off = 32; off; off >>= 1) {
        ss += __shfl_xor(ss, off);
        dd += __shfl_xor(dd, off);
        hh += __shfl_xor(hh, off);
    }
    if (l == 0) {
        float cs = dd / (fmaxf(sqrtf(ss), EPS_) * fmaxf(sqrtf(hh), EPS_));
        pen[b * KP_ + kk] = GAMMA_ * fmaxf(cs - TAU_, 0.f);
    }
}

// ---------------------------------------------------------------- gemm_WpU
__global__ __launch_bounds__(1024) void gemm_WpU(
        const unsigned short* __restrict__ ehs_bf,
        const unsigned short* __restrict__ Bmat,
        unsigned short* __restrict__ Wp, unsigned short* __restrict__ U) {
    const int id = blockIdx.x;               // 160 = 16 b * 10 nt
    const int b = id & 15, nt = id >> 4;
    const int tid = threadIdx.x, w = tid >> 6, l = tid & 63;
    const int lrow = l & 15, lgrp = l >> 4, lk = lgrp * 8;
    __shared__ unsigned short Al[80 * 768];  // 122880 B, swizzled
    char* lds = (char*)Al;

    const unsigned short* Ag = ehs_bf + (size_t)b * KP_ * D_;
    #pragma unroll
    for (int it = 0; it < 8; ++it) {
        int ch = tid + it * 1024;
        if (ch < 7680) {
            int byte = ch * 16, row = byte / 1536;
            int a = byte ^ ((row & 7) << 4);
            *(ushort8v*)(lds + a) = *(const ushort8v*)(Ag + ch * 8);
        }
    }
    const int n0 = nt * 512 + w * 32;
    const unsigned short* Br = Bmat + (size_t)(n0 + lrow) * D_ + lk;
    bf16x8 bC[2], bN[2];
    #pragma unroll
    for (int nf = 0; nf < 2; ++nf)
        bC[nf] = *(const bf16x8*)(Br + (size_t)nf * 16 * D_);
    __syncthreads();

    f32x4 acc[5][2];
    #pragma unroll
    for (int mf = 0; mf < 5; ++mf)
        #pragma unroll
        for (int nf = 0; nf < 2; ++nf) acc[mf][nf] = (f32x4){0.f, 0.f, 0.f, 0.f};
    #pragma unroll
    for (int ks = 0; ks < D_ / 32; ++ks) {
        if (ks < D_ / 32 - 1) {
            #pragma unroll
            for (int nf = 0; nf < 2; ++nf)
                bN[nf] = *(const bf16x8*)(Br + (size_t)nf * 16 * D_ + (ks + 1) * 32);
        }
        bf16x8 af[5];
        #pragma unroll
        for (int mf = 0; mf < 5; ++mf) {
            int row = mf * 16 + lrow;
            int a = (row * 1536 + (ks * 32 + lk) * 2) ^ ((row & 7) << 4);
            af[mf] = *(const bf16x8*)(lds + a);
        }
        __builtin_amdgcn_s_setprio(1);
        #pragma unroll
        for (int mf = 0; mf < 5; ++mf)
            #pragma unroll
            for (int nf = 0; nf < 2; ++nf)
                acc[mf][nf] = __builtin_amdgcn_mfma_f32_16x16x32_bf16(
                    af[mf], bC[nf], acc[mf][nf], 0, 0, 0);
        __builtin_amdgcn_s_setprio(0);
        #pragma unroll
        for (int nf = 0; nf < 2; ++nf) bC[nf] = bN[nf];
    }
    #pragma unroll
    for (int nf = 0; nf < 2; ++nf) {
        const int col = n0 + nf * 16 + lrow;
        if (col < 2560) {
            const int h = col / C_, c = col % C_;
            #pragma unroll
            for (int mf = 0; mf < 5; ++mf)
                #pragma unroll
                for (int r = 0; r < 4; ++r) {
                    int kk = mf * 16 + lgrp * 4 + r;
                    Wp[((size_t)b * NP_ + h * KP_ + kk) * C_ + c] = f2bf(acc[mf][nf][r]);
                }
        } else {
            const int n2 = col - 2560;
            const int h = n2 / C_, c = n2 % C_;
            #pragma unroll
            for (int mf = 0; mf < 5; ++mf)
                #pragma unroll
                for (int r = 0; r < 4; ++r) {
                    int kk = mf * 16 + lgrp * 4 + r;
                    U[((size_t)b * C_ + c) * NP_ + h * KP_ + kk] = f2bf(acc[mf][nf][r]);
                }
        }
    }
}

// ---------------------------------------------------------------- fused attn
// R16 = R15 + explicit __launch_bounds__(1024, 4): 4 waves/EU -> VGPR cap 512
// (bare (1024) defaulted to a 64-reg cap -> massive spills in R15).
// 512 blocks x 1024 threads (16 waves), 128 S-rows, 160KB LDS; Wp/U staged
// once per 128 rows; acc [5][4]=80/wave via 2-waves-per-head mh-split;
// P via pk regs -> 64-kk chunks [128][128B] dbuf; U [320][128B] K=64 slices.
__global__ __launch_bounds__(1024, 4) void fused_attn(
        const float* __restrict__ hs, const unsigned short* __restrict__ Wp,
        const unsigned short* __restrict__ U, const float* __restrict__ pen,
        const float* __restrict__ bo, float* __restrict__ out) {
    const int id = blockIdx.x;                  // 512 = 8 xcd * 64
    const int xcd = id & 7, rest = id >> 3;     // rest 0..63
    const int b = xcd * 2 + (rest >> 5);        // 2 batches per XCD
    const int s0 = (rest & 31) * 128;
    __shared__ __align__(16) char smem[163840];
    char* HS  = smem;                           // [0,81920)  hs [128][640B] swz
    char* WB  = smem + 81920;                   // [81920,163840) Wp K=64 slice
    char* PC0 = smem;                           // [0,16384)   P chunk dbuf
    char* PC1 = smem + 16384;                   // [16384,32768)
    char* UB  = smem + 32768;                   // [32768,73728) U K=64 slice
    const int tid = threadIdx.x, w = tid >> 6, l = tid & 63;
    const int lrow = l & 15, lgrp = l >> 4;
    const int h = w & 7, mh = w >> 3;           // phase-1: 2 waves per head
    const int mgrp = w & 3, cgrp = w >> 2;      // phase-2: 4m x 4c

    const unsigned short* Wpb = Wp + (size_t)b * NP_ * C_;
    const unsigned short* Ub  = U  + (size_t)b * C_ * NP_;

    // Wp K=64 slice s -> [n 640][128B]; src chunk (q^(n&7)); 5 instr/wave
    auto stage_wp = [&](int s) {
        #pragma unroll
        for (int j = 0; j < 5; ++j) {
            int ch = w * 320 + j * 64 + l;      // 0..5119
            int n = ch >> 3, q = ch & 7;
            gld16(Wpb + (size_t)n * C_ + s * 64 + ((q ^ (n & 7)) << 3),
                  WB + ch * 16);
        }
    };
    // U K=64 slice t -> [c 320][128B]; src chunk (q^(c&7)); 3/2 instr/wave
    auto stage_u = [&](int t) {
        if (w < 8) {
            #pragma unroll
            for (int j = 0; j < 3; ++j) {
                int ch = w * 192 + j * 64 + l;  // 0..1535
                int c = ch >> 3, q = ch & 7;
                gld16(Ub + (size_t)c * NP_ + t * 64 + ((q ^ (c & 7)) << 3),
                      UB + ch * 16);
            }
        } else {
            #pragma unroll
            for (int j = 0; j < 2; ++j) {
                int ch = 1536 + (w - 8) * 128 + j * 64 + l;  // 1536..2559
                int c = ch >> 3, q = ch & 7;
                gld16(Ub + (size_t)c * NP_ + t * 64 + ((q ^ (c & 7)) << 3),
                      UB + ch * 16);
            }
        }
    };

    // ---- prologue: hs 128x320 f32 -> bf16 into HS (swizzled), sync, slice 0
    const float4* hv = (const float4*)(hs + ((size_t)b * S_ + s0) * C_);
    #pragma unroll
    for (int it = 0; it < 10; ++it) {           // 10*1024 = 10240 float4
        int i = tid + it * 1024;
        float4 v = hv[i];
        int r = i / 80, c = (i * 4) % C_;
        ushort4 u;
        u.x = f2bf(v.x); u.y = f2bf(v.y); u.z = f2bf(v.z); u.w = f2bf(v.w);
        int a = (r * 640 + c * 2) ^ ((r & 7) << 4);
        *(ushort4*)(HS + a) = u;
    }
    __syncthreads();        // drains hv vmem + hs ds_writes; HS visible
    stage_wp(0);

    // ---- phase 1: D[kk][m], 5 K=64 slices, single WB, stage-after-read
    f32x4 acc[5][4];
    #pragma unroll
    for (int nf = 0; nf < 5; ++nf)
        #pragma unroll
        for (int mf = 0; mf < 4; ++mf) acc[nf][mf] = (f32x4){0.f, 0.f, 0.f, 0.f};
    #pragma unroll
    for (int s = 0; s < 5; ++s) {
        WAITV(0);                               // own chunks of slice s done
        BAR();                                  // slice s fully landed
        bf16x8 bC[5][2], hf[4][2];
        #pragma unroll
        for (int nf = 0; nf < 5; ++nf) {
            int n = h * KP_ + nf * 16 + lrow;
            #pragma unroll
            for (int ss = 0; ss < 2; ++ss)
                bC[nf][ss] = *(const bf16x8*)(WB + n * 128 +
                    ((ss * 64 + lgrp * 16) ^ ((n & 7) << 4)));
        }
        #pragma unroll
        for (int mf = 0; mf < 4; ++mf) {
            int row = mh * 64 + mf * 16 + lrow;
            #pragma unroll
            for (int ss = 0; ss < 2; ++ss) {
                int ks32 = 2 * s + ss;
                int a = (row * 640 + ks32 * 64 + lgrp * 16) ^ ((row & 7) << 4);
                hf[mf][ss] = *(const bf16x8*)(HS + a);
            }
        }
        WAITLG();                               // reads in regs
        BAR();                                  // all waves done reading WB
        if (s < 4) stage_wp(s + 1);             // refill; lands under MFMA
        __builtin_amdgcn_s_setprio(1);
        #pragma unroll
        for (int ss = 0; ss < 2; ++ss)
            #pragma unroll
            for (int nf = 0; nf < 5; ++nf)
                #pragma unroll
                for (int mf = 0; mf < 4; ++mf)
                    acc[nf][mf] = __builtin_amdgcn_mfma_f32_16x16x32_bf16(
                        bC[nf][ss], hf[mf][ss], acc[nf][mf], 0, 0, 0);
        __builtin_amdgcn_s_setprio(0);
    }
    // s=4 post-read BAR certified HS + WB reads done everywhere.

    // issue U slice 0 now (overlaps softmax); then penalty loads
    stage_u(0);
    float4 pv4[5];
    #pragma unroll
    for (int nf = 0; nf < 5; ++nf)
        pv4[nf] = *(const float4*)(pen + b * KP_ + nf * 16 + lgrp * 4);

    // ---- softmax + pack P into pk regs (20 VGPR, live through phase 2)
    ushort4 pk[4][5];
    #pragma unroll
    for (int mf = 0; mf < 4; ++mf) {
        float mx = -1e30f;
        #pragma unroll
        for (int nf = 0; nf < 5; ++nf)
            #pragma unroll
            for (int r = 0; r < 4; ++r) {
                float x = acc[nf][mf][r] - ((const float*)&pv4[nf])[r];
                if (nf == 4 && r >= 1) x = (lgrp == 3) ? -1e30f : x;  // kk 77..79
                acc[nf][mf][r] = x;
                mx = fmaxf(mx, x);
            }
        mx = fmaxf(mx, __shfl_xor(mx, 16));
        mx = fmaxf(mx, __shfl_xor(mx, 32));
        float sum = 0.f;
        #pragma unroll
        for (int nf = 0; nf < 5; ++nf)
            #pragma unroll
            for (int r = 0; r < 4; ++r) {
                float e = __expf(acc[nf][mf][r] - mx);
                acc[nf][mf][r] = e; sum += e;
            }
        sum += __shfl_xor(sum, 16);
        sum += __shfl_xor(sum, 32);
        float inv = 1.f / sum;
        #pragma unroll
        for (int nf = 0; nf < 5; ++nf) {
            ushort4 u;
            u.x = f2bf(acc[nf][mf][0] * inv);
            u.y = f2bf(acc[nf][mf][1] * inv);
            u.z = f2bf(acc[nf][mf][2] * inv);
            u.w = f2bf(acc[nf][mf][3] * inv);
            pk[mf][nf] = u;
        }
    }

    // head-0 waves write P chunk 0 (kk 0..63 = nf 0..3) into PC0
    if (h == 0) {
        #pragma unroll
        for (int nf = 0; nf < 4; ++nf) {
            int kk2 = (nf * 16 + lgrp * 4) * 2;
            #pragma unroll
            for (int mf = 0; mf < 4; ++mf) {
                int row = mh * 64 + mf * 16 + lrow;
                *(ushort4*)(PC0 + ((row * 128 + kk2) ^ ((row & 7) << 4))) = pk[mf][nf];
            }
        }
    }
    WAITV(0);                                   // U slice 0 (+pen) landed
    WAITLG();                                   // PC0 ds_writes done
    BAR();                                      // PC0 + U0 visible block-wide

    // ---- phase 2: out = P @ U, 10 K=64 steps; P chunks fed from pk regs
    f32x4 acc2[5][2];
    #pragma unroll
    for (int nf = 0; nf < 5; ++nf)
        #pragma unroll
        for (int mf = 0; mf < 2; ++mf) acc2[nf][mf] = (f32x4){0.f, 0.f, 0.f, 0.f};
    #pragma unroll
    for (int t = 0; t < 10; ++t) {
        char* pc = (t & 1) ? PC1 : PC0;
        bf16x8 pa[2][2], uf[5][2];
        #pragma unroll
        for (int mf = 0; mf < 2; ++mf) {
            int row = mgrp * 32 + mf * 16 + lrow;
            #pragma unroll
            for (int ss = 0; ss < 2; ++ss)
                pa[mf][ss] = *(const bf16x8*)(pc +
                    ((row * 128 + ss * 64 + lgrp * 16) ^ ((row & 7) << 4)));
        }
        #pragma unroll
        for (int nf = 0; nf < 5; ++nf) {
            int c = cgrp * KP_ + nf * 16 + lrow;
            #pragma unroll
            for (int ss = 0; ss < 2; ++ss)
                uf[nf][ss] = *(const bf16x8*)(UB + c * 128 +
                    ((ss * 64 + lgrp * 16) ^ ((c & 7) << 4)));
        }
        WAITLG();                               // reads in regs
        BAR();                                  // all waves done reading pc+UB
        if (t < 9) {
            char* pcn = ((t + 1) & 1) ? PC1 : PC0;
            #pragma unroll
            for (int nf = 0; nf < 5; ++nf) {
                if (((h * KP_ + nf * 16) >> 6) == t + 1) {   // wave-uniform
                    int kk2 = (h * KP_ + nf * 16 + lgrp * 4 - (t + 1) * 64) * 2;
                    #pragma unroll
                    for (int mf = 0; mf < 4; ++mf) {
                        int row = mh * 64 + mf * 16 + lrow;
                        *(ushort4*)(pcn + ((row * 128 + kk2) ^ ((row & 7) << 4)))
                            = pk[mf][nf];
                    }
                }
            }
            stage_u(t + 1);                     // refill UB; lands under MFMA
        }
        __builtin_amdgcn_s_setprio(1);
        #pragma unroll
        for (int ss = 0; ss < 2; ++ss)
            #pragma unroll
            for (int nf = 0; nf < 5; ++nf)
                #pragma unroll
                for (int mf = 0; mf < 2; ++mf)
                    acc2[nf][mf] = __builtin_amdgcn_mfma_f32_16x16x32_bf16(
                        pa[mf][ss], uf[nf][ss], acc2[nf][mf], 0, 0, 0);
        __builtin_amdgcn_s_setprio(0);
        if (t < 9) {
            WAITV(0);                           // own U DMA done
            WAITLG();                           // own PC writes done
            BAR();                              // chunk t+1 + slice t+1 visible
        }
    }

    // ---- epilogue
    float bov[5];
    #pragma unroll
    for (int nf = 0; nf < 5; ++nf) bov[nf] = bo[cgrp * KP_ + nf * 16 + lrow];
    float* op = out + ((size_t)b * S_ + s0) * C_;
    #pragma unroll
    for (int mf = 0; mf < 2; ++mf)
        #pragma unroll
        for (int r = 0; r < 4; ++r)
            #pragma unroll
            for (int nf = 0; nf < 5; ++nf)
                op[(size_t)(mgrp * 32 + mf * 16 + lgrp * 4 + r) * C_ +
                   cgrp * KP_ + nf * 16 + lrow] = acc2[nf][mf][r] + bov[nf];
}

// ---------------------------------------------------------------- launch
extern "C" void kernel_launch(void* const* d_in, const int* in_sizes, int n_in,
                              void* d_out, int out_size, void* d_ws, size_t ws_size,
                              hipStream_t stream) {
    const float* hs   = (const float*)d_in[0];
    const float* ehs  = (const float*)d_in[1];
    const float* harm = (const float*)d_in[2];
    const float* Wq   = (const float*)d_in[3];
    const float* Wk   = (const float*)d_in[4];
    const float* Wv   = (const float*)d_in[5];
    const float* Wo   = (const float*)d_in[6];
    const float* bo   = (const float*)d_in[7];
    float* out = (float*)d_out;

    char* ws = (char*)d_ws;
    unsigned short* ehs_bf = (unsigned short*)(ws);             //  1,966,080
    unsigned short* Bmat   = (unsigned short*)(ws + 1966080);   //  7,864,320
    float*          pen    = (float*)        (ws + 9830400);    //      5,120
    unsigned short* Wp     = (unsigned short*)(ws + 9835520);   //  6,553,600
    unsigned short* U      = (unsigned short*)(ws + 16389120);  //  6,553,600

    build_M <<<dim3(3, 8, 8),  256, 0, stream>>>(Wq, Wk, Wv, Wo, Bmat);
    prep_ehs<<<dim3(20, 16),   256, 0, stream>>>(ehs, harm, ehs_bf, pen);
    gemm_WpU<<<dim3(160),     1024, 0, stream>>>(ehs_bf, Bmat, Wp, U);
    fused_attn<<<dim3(512),   1024, 0, stream>>>(hs, Wp, U, pen, bo, out);
}

// Round 18
// 151.959 us; speedup vs baseline: 2.3835x; 2.3647x over previous
//
#include <hip/hip_runtime.h>
#include <hip/hip_bf16.h>

#define B_ 16
#define S_ 4096
#define C_ 320
#define KK_ 77
#define D_ 768
#define H_ 8
#define DH_ 40
#define KP_ 80           // padded keys per head
#define NP_ (H_ * KP_)   // 640
#define TAU_ 0.1f
#define GAMMA_ 1.0f
#define EPS_ 1e-12f

typedef __bf16 bf16x8 __attribute__((ext_vector_type(8)));
typedef float f32x4 __attribute__((ext_vector_type(4)));
typedef unsigned short ushort8v __attribute__((ext_vector_type(8)));
typedef unsigned int u32;

#define WAITV(N)  asm volatile("s_waitcnt vmcnt(" #N ")" ::: "memory")
#define WAITVL(N) asm volatile("s_waitcnt vmcnt(" #N ") lgkmcnt(0)" ::: "memory")
#define WAITLG()  asm volatile("s_waitcnt lgkmcnt(0)" ::: "memory")
#define BAR()     __builtin_amdgcn_s_barrier()

__device__ __forceinline__ unsigned short f2bf(float f) {
    union { float f; unsigned u; } v; v.f = f;
    unsigned r = v.u + 0x7fffu + ((v.u >> 16) & 1u);
    return (unsigned short)(r >> 16);
}

// async 16B-per-lane global->LDS DMA (lds dest = wave-uniform base + lane*16)
__device__ __forceinline__ void gld16(const unsigned short* g, char* l) {
    __builtin_amdgcn_global_load_lds(
        (const __attribute__((address_space(1))) u32*)g,
        (__attribute__((address_space(3))) u32*)l, 16, 0, 0);
}

// ---------------------------------------------------------------- build_M
// 40-col windows (2x parallelism vs 80): grid (3, 8, 16)
__global__ __launch_bounds__(256) void build_M(const float* __restrict__ Wq,
        const float* __restrict__ Wk, const float* __restrict__ Wv,
        const float* __restrict__ Wo, unsigned short* __restrict__ Bmat) {
    const int Dk = blockIdx.x * 256 + threadIdx.x;     // 0..767
    const int h = blockIdx.y;
    const int which = blockIdx.z >> 3;
    const int c0 = (blockIdx.z & 7) * 40;
    __shared__ float wlds[40 * 44];
    for (int i = threadIdx.x; i < 40 * DH_; i += 256) {
        int c = i / DH_, d = i % DH_;
        wlds[c * 44 + d] = which
            ? Wo[(size_t)(h * DH_ + d) * C_ + (c0 + c)]
            : Wq[(size_t)(c0 + c) * C_ + h * DH_ + d];
    }
    float a[DH_];
    const float* Arow = (which ? Wv : Wk) + (size_t)Dk * C_ + h * DH_;
    #pragma unroll
    for (int d = 0; d < DH_; ++d) a[d] = Arow[d];
    __syncthreads();
    const float scale = 0.15811388300841898f;          // 1/sqrt(40)
    for (int c = 0; c < 40; ++c) {
        float s = 0.f;
        #pragma unroll
        for (int q = 0; q < 10; ++q) {
            float4 wv4 = *(const float4*)&wlds[c * 44 + q * 4];
            s += a[q * 4 + 0] * wv4.x + a[q * 4 + 1] * wv4.y
               + a[q * 4 + 2] * wv4.z + a[q * 4 + 3] * wv4.w;
        }
        if (!which) s *= scale;
        int n = which * 2560 + h * C_ + c0 + c;
        Bmat[(size_t)n * D_ + Dk] = f2bf(s);
    }
}

// ---------------------------------------------------------------- prep_ehs
__global__ __launch_bounds__(256) void prep_ehs(const float* __restrict__ ehs,
        const float* __restrict__ harm, unsigned short* __restrict__ ehs_bf,
        float* __restrict__ pen) {
    const int w = threadIdx.x >> 6, l = threadIdx.x & 63;
    const int kk = blockIdx.x * 4 + w, b = blockIdx.y;
    const size_t obase = ((size_t)b * KP_ + kk) * D_;
    if (kk >= KK_) {
        #pragma unroll
        for (int j = 0; j < 12; ++j) ehs_bf[obase + l + j * 64] = 0;
        if (l == 0) pen[b * KP_ + kk] = 0.f;
        return;
    }
    const float* er = ehs + ((size_t)b * KK_ + kk) * D_;
    float ss = 0.f, dd = 0.f, hh = 0.f;
    #pragma unroll
    for (int j = 0; j < 12; ++j) {
        float e = er[l + j * 64], hv = harm[l + j * 64];
        ehs_bf[obase + l + j * 64] = f2bf(e);
        ss += e * e; dd += e * hv; hh += hv * hv;
    }
    #pragma unroll
    for (int off = 32; off; off >>= 1) {
        ss += __shfl_xor(ss, off);
        dd += __shfl_xor(dd, off);
        hh += __shfl_xor(hh, off);
    }
    if (l == 0) {
        float cs = dd / (fmaxf(sqrtf(ss), EPS_) * fmaxf(sqrtf(hh), EPS_));
        pen[b * KP_ + kk] = GAMMA_ * fmaxf(cs - TAU_, 0.f);
    }
}

// ---------------------------------------------------------------- gemm_WpU
// 320 blocks x 512 threads (16b x 20nt, 8 waves x 32 cols) -> all CUs busy.
__global__ __launch_bounds__(512) void gemm_WpU(
        const unsigned short* __restrict__ ehs_bf,
        const unsigned short* __restrict__ Bmat,
        unsigned short* __restrict__ Wp, unsigned short* __restrict__ U) {
    const int id = blockIdx.x;               // 320 = 16 b * 20 nt
    const int b = id & 15, nt = id >> 4;
    const int tid = threadIdx.x, w = tid >> 6, l = tid & 63;
    const int lrow = l & 15, lgrp = l >> 4, lk = lgrp * 8;
    __shared__ unsigned short Al[80 * 768];  // 122880 B, swizzled
    char* lds = (char*)Al;

    const unsigned short* Ag = ehs_bf + (size_t)b * KP_ * D_;
    #pragma unroll
    for (int it = 0; it < 15; ++it) {
        int ch = tid + it * 512;
        if (ch < 7680) {
            int byte = ch * 16, row = byte / 1536;
            int a = byte ^ ((row & 7) << 4);
            *(ushort8v*)(lds + a) = *(const ushort8v*)(Ag + ch * 8);
        }
    }
    const int n0 = nt * 256 + w * 32;
    const unsigned short* Br = Bmat + (size_t)(n0 + lrow) * D_ + lk;
    bf16x8 bC[2], bN[2];
    #pragma unroll
    for (int nf = 0; nf < 2; ++nf)
        bC[nf] = *(const bf16x8*)(Br + (size_t)nf * 16 * D_);
    __syncthreads();

    f32x4 acc[5][2];
    #pragma unroll
    for (int mf = 0; mf < 5; ++mf)
        #pragma unroll
        for (int nf = 0; nf < 2; ++nf) acc[mf][nf] = (f32x4){0.f, 0.f, 0.f, 0.f};
    #pragma unroll
    for (int ks = 0; ks < D_ / 32; ++ks) {
        if (ks < D_ / 32 - 1) {
            #pragma unroll
            for (int nf = 0; nf < 2; ++nf)
                bN[nf] = *(const bf16x8*)(Br + (size_t)nf * 16 * D_ + (ks + 1) * 32);
        }
        bf16x8 af[5];
        #pragma unroll
        for (int mf = 0; mf < 5; ++mf) {
            int row = mf * 16 + lrow;
            int a = (row * 1536 + (ks * 32 + lk) * 2) ^ ((row & 7) << 4);
            af[mf] = *(const bf16x8*)(lds + a);
        }
        __builtin_amdgcn_s_setprio(1);
        #pragma unroll
        for (int mf = 0; mf < 5; ++mf)
            #pragma unroll
            for (int nf = 0; nf < 2; ++nf)
                acc[mf][nf] = __builtin_amdgcn_mfma_f32_16x16x32_bf16(
                    af[mf], bC[nf], acc[mf][nf], 0, 0, 0);
        __builtin_amdgcn_s_setprio(0);
        #pragma unroll
        for (int nf = 0; nf < 2; ++nf) bC[nf] = bN[nf];
    }
    #pragma unroll
    for (int nf = 0; nf < 2; ++nf) {
        const int col = n0 + nf * 16 + lrow;
        if (col < 2560) {
            const int h = col / C_, c = col % C_;
            #pragma unroll
            for (int mf = 0; mf < 5; ++mf)
                #pragma unroll
                for (int r = 0; r < 4; ++r) {
                    int kk = mf * 16 + lgrp * 4 + r;
                    Wp[((size_t)b * NP_ + h * KP_ + kk) * C_ + c] = f2bf(acc[mf][nf][r]);
                }
        } else {
            const int n2 = col - 2560;
            const int h = n2 / C_, c = n2 % C_;
            #pragma unroll
            for (int mf = 0; mf < 5; ++mf)
                #pragma unroll
                for (int r = 0; r < 4; ++r) {
                    int kk = mf * 16 + lgrp * 4 + r;
                    U[((size_t)b * C_ + c) * NP_ + h * KP_ + kk] = f2bf(acc[mf][nf][r]);
                }
        }
    }
}

// ---------------------------------------------------------------- fused attn
// R12 (verified 127us): 1024 blocks x 512 threads (8 waves), 64 S-rows,
// 160KB LDS, 1 block/CU. FULL-L2-LINE staging: K=64 slices, each LDS row gets
// 128B contiguous from global; source-side involution swizzle (q^(n&7)) <->
// read XOR ((n&7)<<4). Phase 1: HS 40KB + single 80KB Wp slice buf. Phase 2:
// P 80KB + 2x40KB U slice bufs.
__global__ __launch_bounds__(512, 2) void fused_attn(
        const float* __restrict__ hs, const unsigned short* __restrict__ Wp,
        const unsigned short* __restrict__ U, const float* __restrict__ pen,
        const float* __restrict__ bo, float* __restrict__ out) {
    const int id = blockIdx.x;                  // 1024 = 8 xcd * 128
    const int xcd = id & 7, rest = id >> 3;
    const int b = xcd * 2 + (rest >> 6);        // 2 batches per XCD
    const int s0 = (rest & 63) * 64;
    __shared__ __align__(16) char smem[163840];
    char* HS = smem;                            // [0,40960)   hs tile (phase 1)
    char* WB = smem + 40960;                    // [40960,122880) Wp K=64 slice
    char* PB = smem;                            // [0,81920)   P (phase 2)
    char* U0 = smem + 81920;                    // [81920,122880)  U slice buf
    char* U1 = smem + 122880;                   // [122880,163840) U slice buf
    const int tid = threadIdx.x, w = tid >> 6, l = tid & 63;
    const int lrow = l & 15, lgrp = l >> 4, lk = lgrp * 8;
    const int h = w;                            // phase-1: wave = head
    const int mgrp = w & 1, ngrp = w >> 1;      // phase-2: 2m x 4n

    const unsigned short* Wpb = Wp + ((size_t)b * NP_) * C_;
    const unsigned short* Ub  = U  + ((size_t)b * C_) * NP_;

    // Wp K=64 slice s -> LDS [n 640][128B]; chunk ch = n*8+q; dest linear
    // ch*16; src 16B-chunk (q ^ (n&7)) of row n's slice window. 10 instr/wave.
    auto stage_wp = [&](int s) {
        #pragma unroll
        for (int j = 0; j < 10; ++j) {
            int ch = w * 640 + j * 64 + l;      // 0..5119
            int n = ch >> 3, q = ch & 7;
            gld16(Wpb + (size_t)n * C_ + s * 64 + ((q ^ (n & 7)) << 3),
                  WB + ch * 16);
        }
    };
    // U K=64 slice t -> LDS [c 320][128B]; same scheme. 5 instr/wave.
    auto stage_u = [&](int t, char* buf) {
        #pragma unroll
        for (int j = 0; j < 5; ++j) {
            int ch = w * 320 + j * 64 + l;      // 0..2559
            int c = ch >> 3, q = ch & 7;
            gld16(Ub + (size_t)c * NP_ + t * 64 + ((q ^ (c & 7)) << 3),
                  buf + ch * 16);
        }
    };

    // ---- prologue: pen + hs loads, convert/ds_write HS, sync, issue slice 0
    float4 pv4[5];
    #pragma unroll
    for (int nf = 0; nf < 5; ++nf)
        pv4[nf] = *(const float4*)(pen + b * KP_ + nf * 16 + lgrp * 4);
    const float4* hv = (const float4*)(hs + ((size_t)b * S_ + s0) * C_);
    #pragma unroll
    for (int it = 0; it < 10; ++it) {           // 10*512 = 5120 float4 = 64x320
        int i = tid + it * 512;
        float4 v = hv[i];
        int r = i / 80, c = (i * 4) % C_;
        ushort4 u;
        u.x = f2bf(v.x); u.y = f2bf(v.y); u.z = f2bf(v.z); u.w = f2bf(v.w);
        int a = (r * 640 + c * 2) ^ ((r & 7) << 4);
        *(ushort4*)(HS + a) = u;
    }
    __syncthreads();        // drains hv/pen vmem + hs ds_writes; HS visible
    stage_wp(0);

    // ---- phase 1: D[kk][m], 5 K=64 slices, single buf; DMA(s+1) || MFMA(s)
    f32x4 acc[5][4];
    #pragma unroll
    for (int nf = 0; nf < 5; ++nf)
        #pragma unroll
        for (int mf = 0; mf < 4; ++mf) acc[nf][mf] = (f32x4){0.f, 0.f, 0.f, 0.f};
    #pragma unroll
    for (int s = 0; s < 5; ++s) {
        WAITV(0);                               // own chunks of slice s done
        BAR();                                  // slice s fully landed
        bf16x8 bC[5][2], hf[4][2];
        #pragma unroll
        for (int nf = 0; nf < 5; ++nf) {
            int n = h * KP_ + nf * 16 + lrow;
            #pragma unroll
            for (int ss = 0; ss < 2; ++ss)
                bC[nf][ss] = *(const bf16x8*)(WB + n * 128 +
                    ((ss * 64 + lgrp * 16) ^ ((n & 7) << 4)));
        }
        #pragma unroll
        for (int mf = 0; mf < 4; ++mf) {
            int row = mf * 16 + lrow;
            #pragma unroll
            for (int ss = 0; ss < 2; ++ss) {
                int ks32 = 2 * s + ss;
                int a = (row * 640 + (ks32 * 32 + lk) * 2) ^ ((row & 7) << 4);
                hf[mf][ss] = *(const bf16x8*)(HS + a);
            }
        }
        WAITLG();                               // reads in regs
        BAR();                                  // all waves done reading WB
        if (s < 4) stage_wp(s + 1);             // refill; lands under MFMA
        __builtin_amdgcn_s_setprio(1);
        #pragma unroll
        for (int ss = 0; ss < 2; ++ss)
            #pragma unroll
            for (int nf = 0; nf < 5; ++nf)
                #pragma unroll
                for (int mf = 0; mf < 4; ++mf)
                    acc[nf][mf] = __builtin_amdgcn_mfma_f32_16x16x32_bf16(
                        bC[nf][ss], hf[mf][ss], acc[nf][mf], 0, 0, 0);
        __builtin_amdgcn_s_setprio(0);
    }
    // s=4's post-read BAR certified HS + WB free; no DMA outstanding.

    // ---- transition: stage U slices 0,1; softmax + P write overlap the DMA
    stage_u(0, U0);
    stage_u(1, U1);

    float inv4[4];
    #pragma unroll
    for (int mf = 0; mf < 4; ++mf) {
        float mx = -1e30f;
        #pragma unroll
        for (int nf = 0; nf < 5; ++nf)
            #pragma unroll
            for (int r = 0; r < 4; ++r) {
                float x = acc[nf][mf][r] - ((const float*)&pv4[nf])[r];
                if (nf == 4 && r >= 1) x = (lgrp == 3) ? -1e30f : x;  // kk 77..79
                acc[nf][mf][r] = x;
                mx = fmaxf(mx, x);
            }
        mx = fmaxf(mx, __shfl_xor(mx, 16));
        mx = fmaxf(mx, __shfl_xor(mx, 32));
        float s = 0.f;
        #pragma unroll
        for (int nf = 0; nf < 5; ++nf)
            #pragma unroll
            for (int r = 0; r < 4; ++r) {
                float e = __expf(acc[nf][mf][r] - mx);
                acc[nf][mf][r] = e; s += e;
            }
        s += __shfl_xor(s, 16);
        s += __shfl_xor(s, 32);
        inv4[mf] = 1.f / s;
    }

    // write P (bf16) into PB: byte = (m*1280 + col*2) ^ ((m&7)<<4)
    #pragma unroll
    for (int mf = 0; mf < 4; ++mf) {
        const int m = mf * 16 + lrow;
        const float inv = inv4[mf];
        #pragma unroll
        for (int nf = 0; nf < 5; ++nf) {
            ushort4 u;
            u.x = f2bf(acc[nf][mf][0] * inv);
            u.y = f2bf(acc[nf][mf][1] * inv);
            u.z = f2bf(acc[nf][mf][2] * inv);
            u.w = f2bf(acc[nf][mf][3] * inv);
            int a = (m * 1280 + (h * KP_ + nf * 16 + lgrp * 4) * 2) ^ ((m & 7) << 4);
            *(ushort4*)(PB + a) = u;
        }
    }
    WAITVL(5);                                  // U slice0 landed + P writes done
    BAR();                                      // P + U0 visible block-wide

    // ---- phase 2: out = P @ U, 10 K=64 slices, 2-buf counted pipeline
    f32x4 acc2[5][2];
    #pragma unroll
    for (int nf = 0; nf < 5; ++nf)
        #pragma unroll
        for (int mf = 0; mf < 2; ++mf) acc2[nf][mf] = (f32x4){0.f, 0.f, 0.f, 0.f};
    #pragma unroll
    for (int t = 0; t < 10; ++t) {
        if (t > 0) {
            if (t < 9) { WAITV(5); } else { WAITV(0); }   // slice t landed
            BAR();
        }
        char* ub = (t & 1) ? U1 : U0;
        bf16x8 pa[2][2], uf[5][2];
        #pragma unroll
        for (int mf = 0; mf < 2; ++mf) {
            int m = mgrp * 32 + mf * 16 + lrow;
            #pragma unroll
            for (int ss = 0; ss < 2; ++ss) {
                int a = (m * 1280 + (t * 128 + ss * 64 + lgrp * 16)) ^ ((m & 7) << 4);
                pa[mf][ss] = *(const bf16x8*)(PB + a);
            }
        }
        #pragma unroll
        for (int nf = 0; nf < 5; ++nf) {
            int c = ngrp * KP_ + nf * 16 + lrow;
            #pragma unroll
            for (int ss = 0; ss < 2; ++ss)
                uf[nf][ss] = *(const bf16x8*)(ub + c * 128 +
                    ((ss * 64 + lgrp * 16) ^ ((c & 7) << 4)));
        }
        WAITLG();                               // reads in regs
        BAR();                                  // all waves done reading ub
        if (t < 8) stage_u(t + 2, ub);          // refill; lands under MFMA
        __builtin_amdgcn_s_setprio(1);
        #pragma unroll
        for (int ss = 0; ss < 2; ++ss)
            #pragma unroll
            for (int nf = 0; nf < 5; ++nf)
                #pragma unroll
                for (int mf = 0; mf < 2; ++mf)
                    acc2[nf][mf] = __builtin_amdgcn_mfma_f32_16x16x32_bf16(
                        pa[mf][ss], uf[nf][ss], acc2[nf][mf], 0, 0, 0);
        __builtin_amdgcn_s_setprio(0);
    }

    // ---- epilogue
    float bov[5];
    #pragma unroll
    for (int nf = 0; nf < 5; ++nf) bov[nf] = bo[ngrp * KP_ + nf * 16 + lrow];
    float* op = out + ((size_t)b * S_ + s0) * C_;
    #pragma unroll
    for (int mf = 0; mf < 2; ++mf)
        #pragma unroll
        for (int r = 0; r < 4; ++r)
            #pragma unroll
            for (int nf = 0; nf < 5; ++nf)
                op[(size_t)(mgrp * 32 + mf * 16 + lgrp * 4 + r) * C_ +
                   ngrp * KP_ + nf * 16 + lrow] = acc2[nf][mf][r] + bov[nf];
}

// ---------------------------------------------------------------- launch
extern "C" void kernel_launch(void* const* d_in, const int* in_sizes, int n_in,
                              void* d_out, int out_size, void* d_ws, size_t ws_size,
                              hipStream_t stream) {
    const float* hs   = (const float*)d_in[0];
    const float* ehs  = (const float*)d_in[1];
    const float* harm = (const float*)d_in[2];
    const float* Wq   = (const float*)d_in[3];
    const float* Wk   = (const float*)d_in[4];
    const float* Wv   = (const float*)d_in[5];
    const float* Wo   = (const float*)d_in[6];
    const float* bo   = (const float*)d_in[7];
    float* out = (float*)d_out;

    char* ws = (char*)d_ws;
    unsigned short* ehs_bf = (unsigned short*)(ws);             //  1,966,080
    unsigned short* Bmat   = (unsigned short*)(ws + 1966080);   //  7,864,320
    float*          pen    = (float*)        (ws + 9830400);    //      5,120
    unsigned short* Wp     = (unsigned short*)(ws + 9835520);   //  6,553,600
    unsigned short* U      = (unsigned short*)(ws + 16389120);  //  6,553,600

    build_M <<<dim3(3, 8, 16), 256, 0, stream>>>(Wq, Wk, Wv, Wo, Bmat);
    prep_ehs<<<dim3(20, 16),   256, 0, stream>>>(ehs, harm, ehs_bf, pen);
    gemm_WpU<<<dim3(320),      512, 0, stream>>>(ehs_bf, Bmat, Wp, U);
    fused_attn<<<dim3(1024),   512, 0, stream>>>(hs, Wp, U, pen, bo, out);
}

// Round 19
// 151.127 us; speedup vs baseline: 2.3967x; 1.0055x over previous
//
#include <hip/hip_runtime.h>
#include <hip/hip_bf16.h>

#define B_ 16
#define S_ 4096
#define C_ 320
#define KK_ 77
#define D_ 768
#define H_ 8
#define DH_ 40
#define KP_ 80           // padded keys per head
#define NP_ (H_ * KP_)   // 640
#define TAU_ 0.1f
#define GAMMA_ 1.0f
#define EPS_ 1e-12f

typedef __bf16 bf16x8 __attribute__((ext_vector_type(8)));
typedef float f32x4 __attribute__((ext_vector_type(4)));
typedef unsigned short ushort8v __attribute__((ext_vector_type(8)));
typedef unsigned int u32;

#define WAITV(N)  asm volatile("s_waitcnt vmcnt(" #N ")" ::: "memory")
#define WAITVL(N) asm volatile("s_waitcnt vmcnt(" #N ") lgkmcnt(0)" ::: "memory")
#define WAITLG()  asm volatile("s_waitcnt lgkmcnt(0)" ::: "memory")
#define BAR()     __builtin_amdgcn_s_barrier()

__device__ __forceinline__ unsigned short f2bf(float f) {
    union { float f; unsigned u; } v; v.f = f;
    unsigned r = v.u + 0x7fffu + ((v.u >> 16) & 1u);
    return (unsigned short)(r >> 16);
}

// async 16B-per-lane global->LDS DMA (lds dest = wave-uniform base + lane*16)
__device__ __forceinline__ void gld16(const unsigned short* g, char* l) {
    __builtin_amdgcn_global_load_lds(
        (const __attribute__((address_space(1))) u32*)g,
        (__attribute__((address_space(3))) u32*)l, 16, 0, 0);
}

// ---------------------------------------------------------------- build_M
// 40-col windows: grid (3, 8, 16)
__global__ __launch_bounds__(256) void build_M(const float* __restrict__ Wq,
        const float* __restrict__ Wk, const float* __restrict__ Wv,
        const float* __restrict__ Wo, unsigned short* __restrict__ Bmat) {
    const int Dk = blockIdx.x * 256 + threadIdx.x;     // 0..767
    const int h = blockIdx.y;
    const int which = blockIdx.z >> 3;
    const int c0 = (blockIdx.z & 7) * 40;
    __shared__ float wlds[40 * 44];
    for (int i = threadIdx.x; i < 40 * DH_; i += 256) {
        int c = i / DH_, d = i % DH_;
        wlds[c * 44 + d] = which
            ? Wo[(size_t)(h * DH_ + d) * C_ + (c0 + c)]
            : Wq[(size_t)(c0 + c) * C_ + h * DH_ + d];
    }
    float a[DH_];
    const float* Arow = (which ? Wv : Wk) + (size_t)Dk * C_ + h * DH_;
    #pragma unroll
    for (int d = 0; d < DH_; ++d) a[d] = Arow[d];
    __syncthreads();
    const float scale = 0.15811388300841898f;          // 1/sqrt(40)
    for (int c = 0; c < 40; ++c) {
        float s = 0.f;
        #pragma unroll
        for (int q = 0; q < 10; ++q) {
            float4 wv4 = *(const float4*)&wlds[c * 44 + q * 4];
            s += a[q * 4 + 0] * wv4.x + a[q * 4 + 1] * wv4.y
               + a[q * 4 + 2] * wv4.z + a[q * 4 + 3] * wv4.w;
        }
        if (!which) s *= scale;
        int n = which * 2560 + h * C_ + c0 + c;
        Bmat[(size_t)n * D_ + Dk] = f2bf(s);
    }
}

// ---------------------------------------------------------------- gemm_WpU
// 320 blocks x 512 threads (16b x 20nt). A staged DIRECTLY from ehs f32
// (inline f32->bf16 convert, kk>=77 zeroed) -- prep_ehs kernel eliminated.
// nt==0 blocks also compute the penalty vector (f32-exact, same math).
__global__ __launch_bounds__(512) void gemm_WpU(
        const float* __restrict__ ehs, const float* __restrict__ harm,
        const unsigned short* __restrict__ Bmat,
        unsigned short* __restrict__ Wp, unsigned short* __restrict__ U,
        float* __restrict__ pen) {
    const int id = blockIdx.x;               // 320 = 16 b * 20 nt
    const int b = id & 15, nt = id >> 4;
    const int tid = threadIdx.x, w = tid >> 6, l = tid & 63;
    const int lrow = l & 15, lgrp = l >> 4, lk = lgrp * 8;
    __shared__ unsigned short Al[80 * 768];  // 122880 B, swizzled
    char* lds = (char*)Al;

    const float* Eb = ehs + (size_t)b * KK_ * D_;
    // stage A: 7680 chunks of 8 bf16; chunk ch -> row kk=ch/96, col8=ch%96
    #pragma unroll
    for (int it = 0; it < 15; ++it) {
        int ch = tid + it * 512;             // 0..7679
        int kk = ch / 96, c8 = ch % 96;
        ushort8v v8 = (ushort8v)(unsigned short)0;
        if (kk < KK_) {
            const float4* src = (const float4*)(Eb + (size_t)kk * D_ + c8 * 8);
            float4 a0 = src[0], a1 = src[1];
            v8[0] = f2bf(a0.x); v8[1] = f2bf(a0.y);
            v8[2] = f2bf(a0.z); v8[3] = f2bf(a0.w);
            v8[4] = f2bf(a1.x); v8[5] = f2bf(a1.y);
            v8[6] = f2bf(a1.z); v8[7] = f2bf(a1.w);
        }
        int a = (ch * 16) ^ ((kk & 7) << 4);
        *(ushort8v*)(lds + a) = v8;
    }

    // nt==0: penalty for this batch (wave per row, stride 8)
    if (nt == 0) {
        for (int kk = w; kk < KP_; kk += 8) {
            if (kk < KK_) {
                const float* er = Eb + (size_t)kk * D_;
                float ss = 0.f, dd = 0.f, hh = 0.f;
                #pragma unroll
                for (int j = 0; j < 12; ++j) {
                    float e = er[l + j * 64], hv = harm[l + j * 64];
                    ss += e * e; dd += e * hv; hh += hv * hv;
                }
                #pragma unroll
                for (int off = 32; off; off >>= 1) {
                    ss += __shfl_xor(ss, off);
                    dd += __shfl_xor(dd, off);
                    hh += __shfl_xor(hh, off);
                }
                if (l == 0) {
                    float cs = dd / (fmaxf(sqrtf(ss), EPS_) * fmaxf(sqrtf(hh), EPS_));
                    pen[b * KP_ + kk] = GAMMA_ * fmaxf(cs - TAU_, 0.f);
                }
            } else if (l == 0) {
                pen[b * KP_ + kk] = 0.f;
            }
        }
    }

    const int n0 = nt * 256 + w * 32;
    const unsigned short* Br = Bmat + (size_t)(n0 + lrow) * D_ + lk;
    bf16x8 bC[2], bN[2];
    #pragma unroll
    for (int nf = 0; nf < 2; ++nf)
        bC[nf] = *(const bf16x8*)(Br + (size_t)nf * 16 * D_);
    __syncthreads();

    f32x4 acc[5][2];
    #pragma unroll
    for (int mf = 0; mf < 5; ++mf)
        #pragma unroll
        for (int nf = 0; nf < 2; ++nf) acc[mf][nf] = (f32x4){0.f, 0.f, 0.f, 0.f};
    #pragma unroll
    for (int ks = 0; ks < D_ / 32; ++ks) {
        if (ks < D_ / 32 - 1) {
            #pragma unroll
            for (int nf = 0; nf < 2; ++nf)
                bN[nf] = *(const bf16x8*)(Br + (size_t)nf * 16 * D_ + (ks + 1) * 32);
        }
        bf16x8 af[5];
        #pragma unroll
        for (int mf = 0; mf < 5; ++mf) {
            int row = mf * 16 + lrow;
            int a = (row * 1536 + (ks * 32 + lk) * 2) ^ ((row & 7) << 4);
            af[mf] = *(const bf16x8*)(lds + a);
        }
        __builtin_amdgcn_s_setprio(1);
        #pragma unroll
        for (int mf = 0; mf < 5; ++mf)
            #pragma unroll
            for (int nf = 0; nf < 2; ++nf)
                acc[mf][nf] = __builtin_amdgcn_mfma_f32_16x16x32_bf16(
                    af[mf], bC[nf], acc[mf][nf], 0, 0, 0);
        __builtin_amdgcn_s_setprio(0);
        #pragma unroll
        for (int nf = 0; nf < 2; ++nf) bC[nf] = bN[nf];
    }
    #pragma unroll
    for (int nf = 0; nf < 2; ++nf) {
        const int col = n0 + nf * 16 + lrow;
        if (col < 2560) {
            const int h = col / C_, c = col % C_;
            #pragma unroll
            for (int mf = 0; mf < 5; ++mf)
                #pragma unroll
                for (int r = 0; r < 4; ++r) {
                    int kk = mf * 16 + lgrp * 4 + r;
                    Wp[((size_t)b * NP_ + h * KP_ + kk) * C_ + c] = f2bf(acc[mf][nf][r]);
                }
        } else {
            const int n2 = col - 2560;
            const int h = n2 / C_, c = n2 % C_;
            #pragma unroll
            for (int mf = 0; mf < 5; ++mf)
                #pragma unroll
                for (int r = 0; r < 4; ++r) {
                    int kk = mf * 16 + lgrp * 4 + r;
                    U[((size_t)b * C_ + c) * NP_ + h * KP_ + kk] = f2bf(acc[mf][nf][r]);
                }
        }
    }
}

// ---------------------------------------------------------------- fused attn
// R12/R17 (verified 126us): 1024 blocks x 512 threads (8 waves), 64 S-rows,
// 160KB LDS, 1 block/CU. FULL-L2-LINE staging: K=64 slices; source-side
// involution swizzle (q^(n&7)) <-> read XOR ((n&7)<<4).
__global__ __launch_bounds__(512, 2) void fused_attn(
        const float* __restrict__ hs, const unsigned short* __restrict__ Wp,
        const unsigned short* __restrict__ U, const float* __restrict__ pen,
        const float* __restrict__ bo, float* __restrict__ out) {
    const int id = blockIdx.x;                  // 1024 = 8 xcd * 128
    const int xcd = id & 7, rest = id >> 3;
    const int b = xcd * 2 + (rest >> 6);        // 2 batches per XCD
    const int s0 = (rest & 63) * 64;
    __shared__ __align__(16) char smem[163840];
    char* HS = smem;                            // [0,40960)   hs tile (phase 1)
    char* WB = smem + 40960;                    // [40960,122880) Wp K=64 slice
    char* PB = smem;                            // [0,81920)   P (phase 2)
    char* U0 = smem + 81920;                    // [81920,122880)  U slice buf
    char* U1 = smem + 122880;                   // [122880,163840) U slice buf
    const int tid = threadIdx.x, w = tid >> 6, l = tid & 63;
    const int lrow = l & 15, lgrp = l >> 4, lk = lgrp * 8;
    const int h = w;                            // phase-1: wave = head
    const int mgrp = w & 1, ngrp = w >> 1;      // phase-2: 2m x 4n

    const unsigned short* Wpb = Wp + ((size_t)b * NP_) * C_;
    const unsigned short* Ub  = U  + ((size_t)b * C_) * NP_;

    auto stage_wp = [&](int s) {
        #pragma unroll
        for (int j = 0; j < 10; ++j) {
            int ch = w * 640 + j * 64 + l;      // 0..5119
            int n = ch >> 3, q = ch & 7;
            gld16(Wpb + (size_t)n * C_ + s * 64 + ((q ^ (n & 7)) << 3),
                  WB + ch * 16);
        }
    };
    auto stage_u = [&](int t, char* buf) {
        #pragma unroll
        for (int j = 0; j < 5; ++j) {
            int ch = w * 320 + j * 64 + l;      // 0..2559
            int c = ch >> 3, q = ch & 7;
            gld16(Ub + (size_t)c * NP_ + t * 64 + ((q ^ (c & 7)) << 3),
                  buf + ch * 16);
        }
    };

    // ---- prologue: pen + hs loads, convert/ds_write HS, sync, issue slice 0
    float4 pv4[5];
    #pragma unroll
    for (int nf = 0; nf < 5; ++nf)
        pv4[nf] = *(const float4*)(pen + b * KP_ + nf * 16 + lgrp * 4);
    const float4* hv = (const float4*)(hs + ((size_t)b * S_ + s0) * C_);
    #pragma unroll
    for (int it = 0; it < 10; ++it) {           // 10*512 = 5120 float4 = 64x320
        int i = tid + it * 512;
        float4 v = hv[i];
        int r = i / 80, c = (i * 4) % C_;
        ushort4 u;
        u.x = f2bf(v.x); u.y = f2bf(v.y); u.z = f2bf(v.z); u.w = f2bf(v.w);
        int a = (r * 640 + c * 2) ^ ((r & 7) << 4);
        *(ushort4*)(HS + a) = u;
    }
    __syncthreads();        // drains hv/pen vmem + hs ds_writes; HS visible
    stage_wp(0);

    // ---- phase 1: D[kk][m], 5 K=64 slices, single buf; DMA(s+1) || MFMA(s)
    f32x4 acc[5][4];
    #pragma unroll
    for (int nf = 0; nf < 5; ++nf)
        #pragma unroll
        for (int mf = 0; mf < 4; ++mf) acc[nf][mf] = (f32x4){0.f, 0.f, 0.f, 0.f};
    #pragma unroll
    for (int s = 0; s < 5; ++s) {
        WAITV(0);                               // own chunks of slice s done
        BAR();                                  // slice s fully landed
        bf16x8 bC[5][2], hf[4][2];
        #pragma unroll
        for (int nf = 0; nf < 5; ++nf) {
            int n = h * KP_ + nf * 16 + lrow;
            #pragma unroll
            for (int ss = 0; ss < 2; ++ss)
                bC[nf][ss] = *(const bf16x8*)(WB + n * 128 +
                    ((ss * 64 + lgrp * 16) ^ ((n & 7) << 4)));
        }
        #pragma unroll
        for (int mf = 0; mf < 4; ++mf) {
            int row = mf * 16 + lrow;
            #pragma unroll
            for (int ss = 0; ss < 2; ++ss) {
                int ks32 = 2 * s + ss;
                int a = (row * 640 + (ks32 * 32 + lk) * 2) ^ ((row & 7) << 4);
                hf[mf][ss] = *(const bf16x8*)(HS + a);
            }
        }
        WAITLG();                               // reads in regs
        BAR();                                  // all waves done reading WB
        if (s < 4) stage_wp(s + 1);             // refill; lands under MFMA
        __builtin_amdgcn_s_setprio(1);
        #pragma unroll
        for (int ss = 0; ss < 2; ++ss)
            #pragma unroll
            for (int nf = 0; nf < 5; ++nf)
                #pragma unroll
                for (int mf = 0; mf < 4; ++mf)
                    acc[nf][mf] = __builtin_amdgcn_mfma_f32_16x16x32_bf16(
                        bC[nf][ss], hf[mf][ss], acc[nf][mf], 0, 0, 0);
        __builtin_amdgcn_s_setprio(0);
    }
    // s=4's post-read BAR certified HS + WB free; no DMA outstanding.

    // ---- transition: stage U slices 0,1; softmax + P write overlap the DMA
    stage_u(0, U0);
    stage_u(1, U1);

    float inv4[4];
    #pragma unroll
    for (int mf = 0; mf < 4; ++mf) {
        float mx = -1e30f;
        #pragma unroll
        for (int nf = 0; nf < 5; ++nf)
            #pragma unroll
            for (int r = 0; r < 4; ++r) {
                float x = acc[nf][mf][r] - ((const float*)&pv4[nf])[r];
                if (nf == 4 && r >= 1) x = (lgrp == 3) ? -1e30f : x;  // kk 77..79
                acc[nf][mf][r] = x;
                mx = fmaxf(mx, x);
            }
        mx = fmaxf(mx, __shfl_xor(mx, 16));
        mx = fmaxf(mx, __shfl_xor(mx, 32));
        float s = 0.f;
        #pragma unroll
        for (int nf = 0; nf < 5; ++nf)
            #pragma unroll
            for (int r = 0; r < 4; ++r) {
                float e = __expf(acc[nf][mf][r] - mx);
                acc[nf][mf][r] = e; s += e;
            }
        s += __shfl_xor(s, 16);
        s += __shfl_xor(s, 32);
        inv4[mf] = 1.f / s;
    }

    // write P (bf16) into PB: byte = (m*1280 + col*2) ^ ((m&7)<<4)
    #pragma unroll
    for (int mf = 0; mf < 4; ++mf) {
        const int m = mf * 16 + lrow;
        const float inv = inv4[mf];
        #pragma unroll
        for (int nf = 0; nf < 5; ++nf) {
            ushort4 u;
            u.x = f2bf(acc[nf][mf][0] * inv);
            u.y = f2bf(acc[nf][mf][1] * inv);
            u.z = f2bf(acc[nf][mf][2] * inv);
            u.w = f2bf(acc[nf][mf][3] * inv);
            int a = (m * 1280 + (h * KP_ + nf * 16 + lgrp * 4) * 2) ^ ((m & 7) << 4);
            *(ushort4*)(PB + a) = u;
        }
    }
    WAITVL(5);                                  // U slice0 landed + P writes done
    BAR();                                      // P + U0 visible block-wide

    // ---- phase 2: out = P @ U, 10 K=64 slices, 2-buf counted pipeline
    f32x4 acc2[5][2];
    #pragma unroll
    for (int nf = 0; nf < 5; ++nf)
        #pragma unroll
        for (int mf = 0; mf < 2; ++mf) acc2[nf][mf] = (f32x4){0.f, 0.f, 0.f, 0.f};
    #pragma unroll
    for (int t = 0; t < 10; ++t) {
        if (t > 0) {
            if (t < 9) { WAITV(5); } else { WAITV(0); }   // slice t landed
            BAR();
        }
        char* ub = (t & 1) ? U1 : U0;
        bf16x8 pa[2][2], uf[5][2];
        #pragma unroll
        for (int mf = 0; mf < 2; ++mf) {
            int m = mgrp * 32 + mf * 16 + lrow;
            #pragma unroll
            for (int ss = 0; ss < 2; ++ss) {
                int a = (m * 1280 + (t * 128 + ss * 64 + lgrp * 16)) ^ ((m & 7) << 4);
                pa[mf][ss] = *(const bf16x8*)(PB + a);
            }
        }
        #pragma unroll
        for (int nf = 0; nf < 5; ++nf) {
            int c = ngrp * KP_ + nf * 16 + lrow;
            #pragma unroll
            for (int ss = 0; ss < 2; ++ss)
                uf[nf][ss] = *(const bf16x8*)(ub + c * 128 +
                    ((ss * 64 + lgrp * 16) ^ ((c & 7) << 4)));
        }
        WAITLG();                               // reads in regs
        BAR();                                  // all waves done reading ub
        if (t < 8) stage_u(t + 2, ub);          // refill; lands under MFMA
        __builtin_amdgcn_s_setprio(1);
        #pragma unroll
        for (int ss = 0; ss < 2; ++ss)
            #pragma unroll
            for (int nf = 0; nf < 5; ++nf)
                #pragma unroll
                for (int mf = 0; mf < 2; ++mf)
                    acc2[nf][mf] = __builtin_amdgcn_mfma_f32_16x16x32_bf16(
                        pa[mf][ss], uf[nf][ss], acc2[nf][mf], 0, 0, 0);
        __builtin_amdgcn_s_setprio(0);
    }

    // ---- epilogue
    float bov[5];
    #pragma unroll
    for (int nf = 0; nf < 5; ++nf) bov[nf] = bo[ngrp * KP_ + nf * 16 + lrow];
    float* op = out + ((size_t)b * S_ + s0) * C_;
    #pragma unroll
    for (int mf = 0; mf < 2; ++mf)
        #pragma unroll
        for (int r = 0; r < 4; ++r)
            #pragma unroll
            for (int nf = 0; nf < 5; ++nf)
                op[(size_t)(mgrp * 32 + mf * 16 + lgrp * 4 + r) * C_ +
                   ngrp * KP_ + nf * 16 + lrow] = acc2[nf][mf][r] + bov[nf];
}

// ---------------------------------------------------------------- launch
extern "C" void kernel_launch(void* const* d_in, const int* in_sizes, int n_in,
                              void* d_out, int out_size, void* d_ws, size_t ws_size,
                              hipStream_t stream) {
    const float* hs   = (const float*)d_in[0];
    const float* ehs  = (const float*)d_in[1];
    const float* harm = (const float*)d_in[2];
    const float* Wq   = (const float*)d_in[3];
    const float* Wk   = (const float*)d_in[4];
    const float* Wv   = (const float*)d_in[5];
    const float* Wo   = (const float*)d_in[6];
    const float* bo   = (const float*)d_in[7];
    float* out = (float*)d_out;

    char* ws = (char*)d_ws;
    unsigned short* Bmat   = (unsigned short*)(ws + 1966080);   //  7,864,320
    float*          pen    = (float*)        (ws + 9830400);    //      5,120
    unsigned short* Wp     = (unsigned short*)(ws + 9835520);   //  6,553,600
    unsigned short* U      = (unsigned short*)(ws + 16389120);  //  6,553,600

    build_M <<<dim3(3, 8, 16), 256, 0, stream>>>(Wq, Wk, Wv, Wo, Bmat);
    gemm_WpU<<<dim3(320),      512, 0, stream>>>(ehs, harm, Bmat, Wp, U, pen);
    fused_attn<<<dim3(1024),   512, 0, stream>>>(hs, Wp, U, pen, bo, out);
}